// Round 6
// baseline (305.662 us; speedup 1.0000x reference)
//
#include <hip/hip_runtime.h>

typedef __attribute__((ext_vector_type(8))) short bf16x8;
typedef __attribute__((ext_vector_type(4))) float f32x4;

#define HH 768
#define EE 768
#define BB 32
#define SS 512
#define PP 76
#define KCAND 64
#define MM (BB * PP)     // 2432
#define VV 50257
#define NC (MM * KCAND)  // 155648
#define CAP 16
#define OVF_CAP 4096

// ws byte offsets (16B aligned)
#define OFF_WT    0u          // bf16 768*768  = 1,179,648
#define OFF_AG    1179648u    // bf16 2432*768 = 3,735,552
#define OFF_LMN   4915200u    // bf16 2432*768 = 3,735,552
#define OFF_CUR   8650752u    // int 50257+1 (last = overflow counter)
#define OFF_PERM2 8851968u    // int 50257*16 = 3,216,448
#define OFF_OVF   12068416u   // int 4096

#define WT_BLOCKS 576
#define AG_BLOCKS 304
#define SC_BLOCKS 608        // 608*256 == NC
#define GLN_BLOCKS 152       // 2432 / 16 rows
#define ROW_BLOCKS 12565     // ceil(VV/4)
#define OVF_BLOCKS 32

__device__ inline unsigned short f2bf(float f) {
    unsigned int u = __float_as_uint(f);
    u += 0x7fffu + ((u >> 16) & 1u);
    return (unsigned short)(u >> 16);
}
__device__ inline float bf2f(unsigned short h) {
    return __uint_as_float(((unsigned int)h) << 16);
}

// K1: W transpose+convert -> Wt[e][h] ; gather masked rows -> Ag[m][k] ;
// bucket-scatter candidates (cursors pre-zeroed by hipMemsetAsync).
__global__ __launch_bounds__(256) void prep_scatter_kernel(
    const float* __restrict__ W, unsigned short* __restrict__ Wt,
    const float* __restrict__ seq, const int* __restrict__ mpos,
    unsigned short* __restrict__ Ag, const int* __restrict__ cand,
    int* __restrict__ cursor, int* __restrict__ perm2, int* __restrict__ ovf) {
    const int bid = blockIdx.x;
    if (bid < WT_BLOCKS) {
        __shared__ float tile[32][33];
        const int h0 = (bid % 24) * 32, e0 = (bid / 24) * 32;
        const int c = threadIdx.x & 31, r = threadIdx.x >> 5;
#pragma unroll
        for (int rr = r; rr < 32; rr += 8)
            tile[rr][c] = W[(size_t)(h0 + rr) * EE + e0 + c];
        __syncthreads();
#pragma unroll
        for (int rr = r; rr < 32; rr += 8)
            Wt[(size_t)(e0 + rr) * HH + h0 + c] = f2bf(tile[c][rr]);
    } else if (bid < WT_BLOCKS + AG_BLOCKS) {
        const int m0 = (bid - WT_BLOCKS) * 8;
        const int t = threadIdx.x;
#pragma unroll
        for (int rr = 0; rr < 8; ++rr) {
            const int m = m0 + rr;
            const int b = m / PP, p = m - b * PP;
            const int ps = mpos[b * PP + p];
            const float* srow = seq + (size_t)(b * SS + ps) * HH;
            unsigned short* drow = Ag + (size_t)m * HH;
#pragma unroll
            for (int j = 0; j < 3; ++j)
                drow[t + j * 256] = f2bf(srow[t + j * 256]);
        }
    } else {
        const int i = (bid - WT_BLOCKS - AG_BLOCKS) * 256 + threadIdx.x;
        const int row = cand[i];
        const int slot = atomicAdd(&cursor[row], 1);
        if (slot < CAP) {
            perm2[row * CAP + slot] = i;
        } else {
            const int j = atomicAdd(&cursor[VV], 1);
            if (j < OVF_CAP) ovf[j] = i;
        }
    }
}

// K2: GEMM with full-row tiles (16 rows x 768 cols, BK=32) + fused bias +
// LayerNorm epilogue, writing bf16 lmn directly. B-tile = full Wt k-slab.
// Each wave: 16 rows x 192 cols = 12 16x16 tiles (48 acc VGPRs).
__global__ __launch_bounds__(256) void gemm_ln_kernel(
    const unsigned short* __restrict__ Ag, const unsigned short* __restrict__ Wt,
    const float* __restrict__ bias, const float* __restrict__ gamma,
    const float* __restrict__ beta, unsigned short* __restrict__ lmn) {
    // stride 40 ushort = 80 B = 20 banks: 16-row frag reads are <=2-way (free)
    __shared__ unsigned short Blds[768][40];
    __shared__ unsigned short Alds[16][40];
    __shared__ float cparam[3 * 768];     // bias | gamma | beta
    __shared__ float part[4][16][2];
    const int tid = threadIdx.x, lane = tid & 63, wv = tid >> 6;
    const int m0 = blockIdx.x * 16;
    for (int i = tid; i < 768; i += 256) {
        cparam[i] = bias[i];
        cparam[768 + i] = gamma[i];
        cparam[1536 + i] = beta[i];
    }
    const unsigned short* abase = Ag + (size_t)m0 * HH;
    const int fr = lane & 15, fq = (lane >> 4) * 8;
    const int sc = (tid & 3) * 8;   // k-offset (ushorts)
    const int srb = tid >> 2;       // 0..63
    f32x4 acc[12] = {};

    for (int kk = 0; kk < HH; kk += 32) {
        __syncthreads();
#pragma unroll
        for (int rd = 0; rd < 12; ++rd) {
            const int n = srb + rd * 64;
            *(int4*)&Blds[n][sc] = *(const int4*)(Wt + (size_t)n * HH + kk + sc);
        }
        if (tid < 64)
            *(int4*)&Alds[srb][sc] = *(const int4*)(abase + (size_t)srb * HH + kk + sc);
        __syncthreads();
        const bf16x8 af = *(const bf16x8*)&Alds[fr][fq];
#pragma unroll
        for (int t = 0; t < 12; ++t) {
            const bf16x8 bf = *(const bf16x8*)&Blds[wv * 192 + t * 16 + fr][fq];
            acc[t] = __builtin_amdgcn_mfma_f32_16x16x32_bf16(af, bf, acc[t], 0, 0, 0);
        }
    }
    // bias add + per-row partial stats (lane holds rows (lane>>4)*4+g)
    float s[4] = {}, q[4] = {};
#pragma unroll
    for (int t = 0; t < 12; ++t) {
        const int col = wv * 192 + t * 16 + fr;
        const float b = cparam[col];
#pragma unroll
        for (int g = 0; g < 4; ++g) {
            const float x = acc[t][g] + b;
            acc[t][g] = x;
            s[g] += x; q[g] += x * x;
        }
    }
#pragma unroll
    for (int m2 = 1; m2 < 16; m2 <<= 1) {
#pragma unroll
        for (int g = 0; g < 4; ++g) { s[g] += __shfl_xor(s[g], m2); q[g] += __shfl_xor(q[g], m2); }
    }
    if (fr == 0) {
        const int rq = lane >> 4;
#pragma unroll
        for (int g = 0; g < 4; ++g) { part[wv][rq * 4 + g][0] = s[g]; part[wv][rq * 4 + g][1] = q[g]; }
    }
    __syncthreads();
    float mu[4], rstd[4];
#pragma unroll
    for (int g = 0; g < 4; ++g) {
        const int r = (lane >> 4) * 4 + g;
        const float S = part[0][r][0] + part[1][r][0] + part[2][r][0] + part[3][r][0];
        const float Q = part[0][r][1] + part[1][r][1] + part[2][r][1] + part[3][r][1];
        mu[g] = S * (1.0f / 768.0f);
        rstd[g] = rsqrtf(Q * (1.0f / 768.0f) - mu[g] * mu[g] + 1e-12f);
    }
#pragma unroll
    for (int t = 0; t < 12; ++t) {
        const int col = wv * 192 + t * 16 + fr;
        const float ga = cparam[768 + col], be = cparam[1536 + col];
#pragma unroll
        for (int g = 0; g < 4; ++g) {
            const int r = m0 + (lane >> 4) * 4 + g;
            lmn[(size_t)r * EE + col] = f2bf((acc[t][g] - mu[g]) * rstd[g] * ga + be);
        }
    }
}

// K3: one wave per unique row; emb row fetched once (compulsory only),
// dotted against L2-resident bf16 lmn rows. Tail blocks drain overflow.
__global__ __launch_bounds__(256) void group_logits_kernel(
    const float* __restrict__ emb, const unsigned short* __restrict__ lmn,
    const int* __restrict__ cursor, const int* __restrict__ perm2,
    const int* __restrict__ ovf, const int* __restrict__ cand,
    float* __restrict__ out) {
    const int lane = threadIdx.x & 63;
    const int bid = blockIdx.x;
    if (bid < ROW_BLOCKS) {
        const int r = bid * 4 + (threadIdx.x >> 6);
        if (r >= VV) return;
        int c = cursor[r];
        if (c == 0) return;
        if (c > CAP) c = CAP;
        const float4* e4 = (const float4*)(emb + (size_t)r * EE);
        const float4 E0 = e4[lane * 2], E1 = e4[lane * 2 + 1], E2 = e4[128 + lane];
        const int l8 = lane * 8, l4 = 512 + lane * 4;
        const int base = r * CAP;
        for (int o = 0; o < c; o += 4) {
            const int nn = c - o;
            int idxv[4]; bf16x8 c8[4]; ushort4 c4v[4];
#pragma unroll
            for (int j = 0; j < 4; ++j) {
                const int jj = (j < nn) ? j : 0;
                const int idx = perm2[base + o + jj];
                idxv[j] = idx;
                const unsigned short* lrow = lmn + (size_t)(idx >> 6) * EE;
                c8[j] = *(const bf16x8*)(lrow + l8);
                c4v[j] = *(const ushort4*)(lrow + l4);
            }
            float d[4];
#pragma unroll
            for (int j = 0; j < 4; ++j) {
                d[j] = bf2f((unsigned short)c8[j][0]) * E0.x
                     + bf2f((unsigned short)c8[j][1]) * E0.y
                     + bf2f((unsigned short)c8[j][2]) * E0.z
                     + bf2f((unsigned short)c8[j][3]) * E0.w
                     + bf2f((unsigned short)c8[j][4]) * E1.x
                     + bf2f((unsigned short)c8[j][5]) * E1.y
                     + bf2f((unsigned short)c8[j][6]) * E1.z
                     + bf2f((unsigned short)c8[j][7]) * E1.w
                     + bf2f(c4v[j].x) * E2.x + bf2f(c4v[j].y) * E2.y
                     + bf2f(c4v[j].z) * E2.z + bf2f(c4v[j].w) * E2.w;
            }
#pragma unroll
            for (int m2 = 32; m2; m2 >>= 1) {
#pragma unroll
                for (int j = 0; j < 4; ++j) d[j] += __shfl_xor(d[j], m2);
            }
            if (lane == 0) {
#pragma unroll
                for (int j = 0; j < 4; ++j)
                    if (j < nn) out[idxv[j]] = d[j];
            }
        }
    } else {
        const int nov0 = cursor[VV];
        const int nov = nov0 < OVF_CAP ? nov0 : OVF_CAP;
        const int wid = (bid - ROW_BLOCKS) * 4 + (threadIdx.x >> 6);
        const int l8 = lane * 8, l4 = 512 + lane * 4;
        for (int j = wid; j < nov; j += OVF_BLOCKS * 4) {
            const int idx = ovf[j];
            const int r = cand[idx];
            const float4* e4 = (const float4*)(emb + (size_t)r * EE);
            const float4 E0 = e4[lane * 2], E1 = e4[lane * 2 + 1], E2 = e4[128 + lane];
            const unsigned short* lrow = lmn + (size_t)(idx >> 6) * EE;
            const bf16x8 c8 = *(const bf16x8*)(lrow + l8);
            const ushort4 c4v = *(const ushort4*)(lrow + l4);
            float d = bf2f((unsigned short)c8[0]) * E0.x + bf2f((unsigned short)c8[1]) * E0.y
                    + bf2f((unsigned short)c8[2]) * E0.z + bf2f((unsigned short)c8[3]) * E0.w
                    + bf2f((unsigned short)c8[4]) * E1.x + bf2f((unsigned short)c8[5]) * E1.y
                    + bf2f((unsigned short)c8[6]) * E1.z + bf2f((unsigned short)c8[7]) * E1.w
                    + bf2f(c4v.x) * E2.x + bf2f(c4v.y) * E2.y
                    + bf2f(c4v.z) * E2.z + bf2f(c4v.w) * E2.w;
#pragma unroll
            for (int m2 = 32; m2; m2 >>= 1) d += __shfl_xor(d, m2);
            if (lane == 0) out[idx] = d;
        }
    }
}

extern "C" void kernel_launch(void* const* d_in, const int* in_sizes, int n_in,
                              void* d_out, int out_size, void* d_ws, size_t ws_size,
                              hipStream_t stream) {
    const float* seq   = (const float*)d_in[0];
    const int*   mpos  = (const int*)d_in[1];
    const int*   cand  = (const int*)d_in[2];
    const float* emb   = (const float*)d_in[3];
    const float* W     = (const float*)d_in[4];
    const float* bias  = (const float*)d_in[5];
    const float* gamma = (const float*)d_in[6];
    const float* beta  = (const float*)d_in[7];
    float* out = (float*)d_out;

    char* ws = (char*)d_ws;
    unsigned short* Wt    = (unsigned short*)(ws + OFF_WT);
    unsigned short* Ag    = (unsigned short*)(ws + OFF_AG);
    unsigned short* lmn   = (unsigned short*)(ws + OFF_LMN);
    int*            cur   = (int*)(ws + OFF_CUR);
    int*            perm2 = (int*)(ws + OFF_PERM2);
    int*            ovf   = (int*)(ws + OFF_OVF);

    hipMemsetAsync(cur, 0, (VV + 1) * sizeof(int), stream);
    prep_scatter_kernel<<<WT_BLOCKS + AG_BLOCKS + SC_BLOCKS, 256, 0, stream>>>(
        W, Wt, seq, mpos, Ag, cand, cur, perm2, ovf);
    gemm_ln_kernel<<<GLN_BLOCKS, 256, 0, stream>>>(Ag, Wt, bias, gamma, beta, lmn);
    group_logits_kernel<<<ROW_BLOCKS + OVF_BLOCKS, 256, 0, stream>>>(
        emb, lmn, cur, perm2, ovf, cand, out);
}